// Round 6
// baseline (203.293 us; speedup 1.0000x reference)
//
#include <hip/hip_runtime.h>

// Problem constants (from reference setup_inputs)
constexpr int B = 8, C = 3, H = 544, W = 960;
constexpr int KH = 3, KW = 3;
constexpr int HW = H * W;        // 522240
constexpr int WT = 8;            // outputs per thread along W
constexpr int HT = 4;            // output rows per thread
constexpr int WQ = W / WT;       // 120
constexpr int HG = H / HT;       // 136
constexpr int NK = C * KH * KW;  // 27 filter planes
constexpr int BLOCK = 256;
constexpr int TOTAL = B * HG * WQ;   // 130560 threads
constexpr int NBLK = TOTAL / BLOCK;  // 510 blocks (~2/CU, balanced)
static_assert(TOTAL % BLOCK == 0, "grid must be exact");

typedef float f32x4 __attribute__((ext_vector_type(4)));

__device__ __forceinline__ void load_row(const float* xr, bool valid,
                                         bool left, bool right,
                                         float xv[WT + 2]) {
    if (valid) {
        f32x4 m0 = *reinterpret_cast<const f32x4*>(xr);
        f32x4 m1 = *reinterpret_cast<const f32x4*>(xr + 4);
        xv[1] = m0[0]; xv[2] = m0[1]; xv[3] = m0[2]; xv[4] = m0[3];
        xv[5] = m1[0]; xv[6] = m1[1]; xv[7] = m1[2]; xv[8] = m1[3];
        xv[0] = left  ? xr[-1] : 0.f;
        xv[9] = right ? xr[WT] : 0.f;
    } else {
        #pragma unroll
        for (int q = 0; q < WT + 2; ++q) xv[q] = 0.f;
    }
}

__global__ __launch_bounds__(BLOCK) void DynFilter_kernel(
    const float* __restrict__ x,     // [B, C, H, W]
    const float* __restrict__ filt,  // [B, 27, H, W]
    float* __restrict__ out)         // [B, 1, H, W]
{
    int tid = (int)blockIdx.x * BLOCK + (int)threadIdx.x;

    int wq = tid % WQ;
    int t  = tid / WQ;
    int hg = t % HG;
    int b  = t / HG;
    int h0 = hg * HT;          // rows h0 .. h0+3
    int w0 = wq * WT;          // cols w0 .. w0+7
    bool left  = (w0 > 0);
    bool right = (w0 + WT < W);

    // accumulators: 4 rows x 8 cols = 8 float4
    f32x4 a0l = {0,0,0,0}, a0h = {0,0,0,0};
    f32x4 a1l = {0,0,0,0}, a1h = {0,0,0,0};
    f32x4 a2l = {0,0,0,0}, a2h = {0,0,0,0};
    f32x4 a3l = {0,0,0,0}, a3h = {0,0,0,0};

    const float* fbase = filt + (size_t)b * NK * HW + (size_t)h0 * W + w0;

    #pragma unroll
    for (int c = 0; c < C; ++c) {
        const float* xc = x + ((size_t)b * C + c) * HW;

        // x window: image rows h0-1 .. h0+4 (6 rows), cols w0-1 .. w0+8
        float xw[HT + 2][WT + 2];
        load_row(xc + (size_t)(h0 - 1) * W + w0, h0 > 0,     left, right, xw[0]);
        #pragma unroll
        for (int rr = 1; rr <= HT; ++rr)   // rows h0 .. h0+3 always valid
            load_row(xc + (size_t)(h0 - 1 + rr) * W + w0, true, left, right, xw[rr]);
        load_row(xc + (size_t)(h0 + HT) * W + w0, h0 + HT < H, left, right, xw[HT + 1]);

        #pragma unroll
        for (int i = 0; i < KH; ++i) {
            #pragma unroll
            for (int j = 0; j < KW; ++j) {
                int k = c * (KH * KW) + i * KW + j;
                const float* fp = fbase + (size_t)k * HW;
                f32x4 g0l = *reinterpret_cast<const f32x4*>(fp);
                f32x4 g0h = *reinterpret_cast<const f32x4*>(fp + 4);
                f32x4 g1l = *reinterpret_cast<const f32x4*>(fp + W);
                f32x4 g1h = *reinterpret_cast<const f32x4*>(fp + W + 4);
                f32x4 g2l = *reinterpret_cast<const f32x4*>(fp + 2 * W);
                f32x4 g2h = *reinterpret_cast<const f32x4*>(fp + 2 * W + 4);
                f32x4 g3l = *reinterpret_cast<const f32x4*>(fp + 3 * W);
                f32x4 g3h = *reinterpret_cast<const f32x4*>(fp + 3 * W + 4);
                #pragma unroll
                for (int q = 0; q < 4; ++q) {
                    a0l[q] += xw[i    ][j + q]     * g0l[q];
                    a0h[q] += xw[i    ][j + q + 4] * g0h[q];
                    a1l[q] += xw[i + 1][j + q]     * g1l[q];
                    a1h[q] += xw[i + 1][j + q + 4] * g1h[q];
                    a2l[q] += xw[i + 2][j + q]     * g2l[q];
                    a2h[q] += xw[i + 2][j + q + 4] * g2h[q];
                    a3l[q] += xw[i + 3][j + q]     * g3l[q];
                    a3h[q] += xw[i + 3][j + q + 4] * g3h[q];
                }
            }
        }
    }

    float* op = out + (size_t)b * HW + (size_t)h0 * W + w0;
    __builtin_nontemporal_store(a0l, reinterpret_cast<f32x4*>(op));
    __builtin_nontemporal_store(a0h, reinterpret_cast<f32x4*>(op) + 1);
    __builtin_nontemporal_store(a1l, reinterpret_cast<f32x4*>(op + W));
    __builtin_nontemporal_store(a1h, reinterpret_cast<f32x4*>(op + W) + 1);
    __builtin_nontemporal_store(a2l, reinterpret_cast<f32x4*>(op + 2 * W));
    __builtin_nontemporal_store(a2h, reinterpret_cast<f32x4*>(op + 2 * W) + 1);
    __builtin_nontemporal_store(a3l, reinterpret_cast<f32x4*>(op + 3 * W));
    __builtin_nontemporal_store(a3h, reinterpret_cast<f32x4*>(op + 3 * W) + 1);
}

extern "C" void kernel_launch(void* const* d_in, const int* in_sizes, int n_in,
                              void* d_out, int out_size, void* d_ws, size_t ws_size,
                              hipStream_t stream) {
    const float* x    = (const float*)d_in[0];
    const float* filt = (const float*)d_in[1];
    float* out        = (float*)d_out;

    DynFilter_kernel<<<NBLK, BLOCK, 0, stream>>>(x, filt, out);
}

// Round 7
// 183.723 us; speedup vs baseline: 1.1065x; 1.1065x over previous
//
#include <hip/hip_runtime.h>

// Problem constants (from reference setup_inputs)
constexpr int B = 8, C = 3, H = 544, W = 960;
constexpr int KH = 3, KW = 3;
constexpr int HW = H * W;        // 522240
constexpr int WT = 12;           // outputs per thread along W
constexpr int HT = 2;            // output rows per thread
constexpr int WQ = W / WT;       // 80
constexpr int HG = H / HT;       // 272
constexpr int NK = C * KH * KW;  // 27 filter planes
constexpr int BLOCK = 256;
constexpr int TOTAL = B * HG * WQ;   // 174080 threads
constexpr int NBLK = TOTAL / BLOCK;  // 680 blocks
static_assert(TOTAL % BLOCK == 0, "grid must be exact");

typedef float f32x4 __attribute__((ext_vector_type(4)));

__device__ __forceinline__ void load_row(const float* xr, bool valid,
                                         bool left, bool right,
                                         float xv[WT + 2]) {
    if (valid) {
        f32x4 m0 = *reinterpret_cast<const f32x4*>(xr);
        f32x4 m1 = *reinterpret_cast<const f32x4*>(xr + 4);
        f32x4 m2 = *reinterpret_cast<const f32x4*>(xr + 8);
        #pragma unroll
        for (int q = 0; q < 4; ++q) {
            xv[1 + q] = m0[q];
            xv[5 + q] = m1[q];
            xv[9 + q] = m2[q];
        }
        xv[0]      = left  ? xr[-1] : 0.f;
        xv[WT + 1] = right ? xr[WT] : 0.f;
    } else {
        #pragma unroll
        for (int q = 0; q < WT + 2; ++q) xv[q] = 0.f;
    }
}

__global__ __launch_bounds__(BLOCK) void DynFilter_kernel(
    const float* __restrict__ x,     // [B, C, H, W]
    const float* __restrict__ filt,  // [B, 27, H, W]
    float* __restrict__ out)         // [B, 1, H, W]
{
    int tid = (int)blockIdx.x * BLOCK + (int)threadIdx.x;

    int wq = tid % WQ;
    int t  = tid / WQ;
    int hg = t % HG;
    int b  = t / HG;
    int h0 = hg * HT;          // rows h0, h0+1
    int w0 = wq * WT;          // cols w0 .. w0+11
    bool left  = (w0 > 0);
    bool right = (w0 + WT < W);

    // accumulators: 2 rows x 12 cols = 6 float4 (named, static)
    f32x4 a0a = {0,0,0,0}, a0b = {0,0,0,0}, a0c = {0,0,0,0};
    f32x4 a1a = {0,0,0,0}, a1b = {0,0,0,0}, a1c = {0,0,0,0};

    const float* fbase = filt + (size_t)b * NK * HW + (size_t)h0 * W + w0;

    #pragma unroll
    for (int c = 0; c < C; ++c) {
        const float* xc = x + ((size_t)b * C + c) * HW;

        // x window: image rows h0-1 .. h0+2 (4 rows), cols w0-1 .. w0+12
        float xw[HT + 2][WT + 2];
        load_row(xc + (size_t)(h0 - 1) * W + w0, h0 > 0,      left, right, xw[0]);
        load_row(xc + (size_t)(h0    ) * W + w0, true,        left, right, xw[1]);
        load_row(xc + (size_t)(h0 + 1) * W + w0, true,        left, right, xw[2]);
        load_row(xc + (size_t)(h0 + 2) * W + w0, h0 + 2 < H,  left, right, xw[3]);

        #pragma unroll
        for (int i = 0; i < KH; ++i) {
            #pragma unroll
            for (int j = 0; j < KW; ++j) {
                int k = c * (KH * KW) + i * KW + j;
                const float* fp = fbase + (size_t)k * HW;
                f32x4 g0a = *reinterpret_cast<const f32x4*>(fp);
                f32x4 g0b = *reinterpret_cast<const f32x4*>(fp + 4);
                f32x4 g0c = *reinterpret_cast<const f32x4*>(fp + 8);
                f32x4 g1a = *reinterpret_cast<const f32x4*>(fp + W);
                f32x4 g1b = *reinterpret_cast<const f32x4*>(fp + W + 4);
                f32x4 g1c = *reinterpret_cast<const f32x4*>(fp + W + 8);
                #pragma unroll
                for (int q = 0; q < 4; ++q) {
                    a0a[q] += xw[i    ][j + q]     * g0a[q];
                    a0b[q] += xw[i    ][j + q + 4] * g0b[q];
                    a0c[q] += xw[i    ][j + q + 8] * g0c[q];
                    a1a[q] += xw[i + 1][j + q]     * g1a[q];
                    a1b[q] += xw[i + 1][j + q + 4] * g1b[q];
                    a1c[q] += xw[i + 1][j + q + 8] * g1c[q];
                }
            }
        }
    }

    float* op = out + (size_t)b * HW + (size_t)h0 * W + w0;
    __builtin_nontemporal_store(a0a, reinterpret_cast<f32x4*>(op));
    __builtin_nontemporal_store(a0b, reinterpret_cast<f32x4*>(op) + 1);
    __builtin_nontemporal_store(a0c, reinterpret_cast<f32x4*>(op) + 2);
    __builtin_nontemporal_store(a1a, reinterpret_cast<f32x4*>(op + W));
    __builtin_nontemporal_store(a1b, reinterpret_cast<f32x4*>(op + W) + 1);
    __builtin_nontemporal_store(a1c, reinterpret_cast<f32x4*>(op + W) + 2);
}

extern "C" void kernel_launch(void* const* d_in, const int* in_sizes, int n_in,
                              void* d_out, int out_size, void* d_ws, size_t ws_size,
                              hipStream_t stream) {
    const float* x    = (const float*)d_in[0];
    const float* filt = (const float*)d_in[1];
    float* out        = (float*)d_out;

    DynFilter_kernel<<<NBLK, BLOCK, 0, stream>>>(x, filt, out);
}

// Round 8
// 92.798 us; speedup vs baseline: 2.1907x; 1.9798x over previous
//
#include <hip/hip_runtime.h>

// Problem constants (from reference setup_inputs)
constexpr int B = 8, C = 3, H = 544, W = 960;
constexpr int KH = 3, KW = 3;
constexpr int HW = H * W;        // 522240
constexpr int WT = 8;            // outputs per thread along W
constexpr int HT = 2;            // output rows per thread
constexpr int WQ = W / WT;       // 120
constexpr int HG = H / HT;       // 272
constexpr int NK = C * KH * KW;  // 27 filter planes
constexpr int BLOCK = 256;
constexpr int TOTAL = B * HG * WQ;   // 261120 threads
constexpr int NBLK = TOTAL / BLOCK;  // 1020 blocks
static_assert(TOTAL % BLOCK == 0, "grid must be exact");

typedef float f32x4 __attribute__((ext_vector_type(4)));

__device__ __forceinline__ void load_row(const float* xr, bool valid,
                                         bool left, bool right,
                                         float xv[WT + 2]) {
    if (valid) {
        f32x4 m0 = *reinterpret_cast<const f32x4*>(xr);
        f32x4 m1 = *reinterpret_cast<const f32x4*>(xr + 4);
        xv[1] = m0[0]; xv[2] = m0[1]; xv[3] = m0[2]; xv[4] = m0[3];
        xv[5] = m1[0]; xv[6] = m1[1]; xv[7] = m1[2]; xv[8] = m1[3];
        xv[0] = left  ? xr[-1] : 0.f;
        xv[9] = right ? xr[WT] : 0.f;
    } else {
        #pragma unroll
        for (int q = 0; q < WT + 2; ++q) xv[q] = 0.f;
    }
}

__global__ __launch_bounds__(BLOCK) void DynFilter_kernel(
    const float* __restrict__ x,     // [B, C, H, W]
    const float* __restrict__ filt,  // [B, 27, H, W]
    float* __restrict__ out)         // [B, 1, H, W]
{
    int tid = (int)blockIdx.x * BLOCK + (int)threadIdx.x;

    int wq = tid % WQ;
    int t  = tid / WQ;
    int hg = t % HG;
    int b  = t / HG;
    int h0 = hg * HT;          // rows h0, h0+1 computed by this thread
    int w0 = wq * WT;
    bool left  = (w0 > 0);
    bool right = (w0 + WT < W);

    f32x4 a00 = {0,0,0,0}, a01 = {0,0,0,0};  // row h0, cols w0..w0+7
    f32x4 a10 = {0,0,0,0}, a11 = {0,0,0,0};  // row h0+1

    // filter base at row h0; row h0+1 reached via +W immediate
    const float* fbase = filt + (size_t)b * NK * HW + (size_t)h0 * W + w0;

    #pragma unroll
    for (int c = 0; c < C; ++c) {
        const float* xc = x + ((size_t)b * C + c) * HW;

        // rolling 4-row x window: rows h0-1 .. h0+2, each 10 cols
        float xva[WT + 2], xvb[WT + 2], xvc[WT + 2], xvd[WT + 2];
        load_row(xc + (size_t)(h0 - 1) * W + w0, h0 > 0,     left, right, xva);
        load_row(xc + (size_t)(h0    ) * W + w0, true,       left, right, xvb);
        load_row(xc + (size_t)(h0 + 1) * W + w0, true,       left, right, xvc);  // h0+1 <= H-1 always
        load_row(xc + (size_t)(h0 + 2) * W + w0, h0 + 2 < H, left, right, xvd);

        #pragma unroll
        for (int i = 0; i < KH; ++i) {
            // static selection of window rows (fully unrolled -> register-resident)
            const float* r0 = (i == 0) ? xva : (i == 1) ? xvb : xvc;  // for output row h0
            const float* r1 = (i == 0) ? xvb : (i == 1) ? xvc : xvd;  // for output row h0+1
            #pragma unroll
            for (int j = 0; j < KW; ++j) {
                int k = c * (KH * KW) + i * KW + j;
                const float* fp = fbase + (size_t)k * HW;
                f32x4 g0 = *reinterpret_cast<const f32x4*>(fp);          // row h0
                f32x4 g1 = *reinterpret_cast<const f32x4*>(fp + 4);
                f32x4 g2 = *reinterpret_cast<const f32x4*>(fp + W);      // row h0+1
                f32x4 g3 = *reinterpret_cast<const f32x4*>(fp + W + 4);
                #pragma unroll
                for (int q = 0; q < 4; ++q) {
                    a00[q] += r0[j + q]     * g0[q];
                    a01[q] += r0[j + q + 4] * g1[q];
                    a10[q] += r1[j + q]     * g2[q];
                    a11[q] += r1[j + q + 4] * g3[q];
                }
            }
        }
    }

    float* op = out + (size_t)b * HW + (size_t)h0 * W + w0;
    __builtin_nontemporal_store(a00, reinterpret_cast<f32x4*>(op));
    __builtin_nontemporal_store(a01, reinterpret_cast<f32x4*>(op) + 1);
    __builtin_nontemporal_store(a10, reinterpret_cast<f32x4*>(op + W));
    __builtin_nontemporal_store(a11, reinterpret_cast<f32x4*>(op + W) + 1);
}

extern "C" void kernel_launch(void* const* d_in, const int* in_sizes, int n_in,
                              void* d_out, int out_size, void* d_ws, size_t ws_size,
                              hipStream_t stream) {
    const float* x    = (const float*)d_in[0];
    const float* filt = (const float*)d_in[1];
    float* out        = (float*)d_out;

    DynFilter_kernel<<<NBLK, BLOCK, 0, stream>>>(x, filt, out);
}